// Round 19
// baseline (1496.707 us; speedup 1.0000x reference)
//
#include <hip/hip_runtime.h>

// ---------------- types / helpers ----------------
typedef float f32x4 __attribute__((ext_vector_type(4)));
typedef __bf16 bf16x8 __attribute__((ext_vector_type(8)));
typedef unsigned short u16x8 __attribute__((ext_vector_type(8)));
typedef unsigned short u16x4 __attribute__((ext_vector_type(4)));

static __device__ __forceinline__ unsigned short f2b(float f) {
  union { float f; unsigned u; } v; v.f = f;
  unsigned r = v.u + 0x7fffu + ((v.u >> 16) & 1u);   // RNE
  return (unsigned short)(r >> 16);
}
static __device__ __forceinline__ float b2f(unsigned short s) {
  union { unsigned u; float f; } v; v.u = ((unsigned)s) << 16;
  return v.f;
}
static __device__ __forceinline__ void gload_lds16(const unsigned short* g, unsigned short* l) {
  __builtin_amdgcn_global_load_lds((const __attribute__((address_space(1))) void*)g,
                                   (__attribute__((address_space(3))) void*)l, 16, 0, 0);
}

#define NEG_BIG -3.0e38f

// ---------------- ws-too-small sentinel ----------------
__global__ __launch_bounds__(256) void fill_sentinel(float* __restrict__ out, int n, float v) {
  int i = blockIdx.x * 256 + threadIdx.x;
  if (i < n) out[i] = v;
}

// -------- transpose + fp32->bf16 (+scale), vectorized u16x4 writes.
// out[orow*K + k] = in[(row0+k)*in_ld + col0+n]*scale.  Requires K%32==0 (all call sites).
// ilv_off < 0: orow = n.  ilv_off >= 0: orow = ((n>>7)<<8) + (n&127) + ilv_off. --------
__global__ __launch_bounds__(256) void transpose_convert(const float* __restrict__ in,
                                                         unsigned short* __restrict__ out,
                                                         int K, int N, int in_ld, int row0, int col0,
                                                         float scale, int ilv_off) {
  __shared__ float tile[32][33];
  const int k0 = blockIdx.y * 32, n0 = blockIdx.x * 32;
  const int tx = threadIdx.x & 31, ty = threadIdx.x >> 5;  // 32 x 8 read layout
#pragma unroll
  for (int i = 0; i < 32; i += 8) {
    int k = k0 + ty + i, n = n0 + tx;
    tile[ty + i][tx] = (k < K && n < N) ? in[(size_t)(row0 + k) * in_ld + col0 + n] : 0.f;
  }
  __syncthreads();
  // write layout: thread owns (n = n0 + tid>>3, 4 consecutive k at k0 + (tid&7)*4)
  const int nl = threadIdx.x >> 3;
  const int n = n0 + nl;
  const int kk = (threadIdx.x & 7) * 4;
  if (n < N) {
    const int orow = (ilv_off >= 0) ? (((n >> 7) << 8) + (n & 127) + ilv_off) : n;
    u16x4 o;
#pragma unroll
    for (int j = 0; j < 4; ++j) o[j] = f2b(tile[kk + j][nl] * scale);
    *reinterpret_cast<u16x4*>(&out[(size_t)orow * K + k0 + kk]) = o;
  }
}

// ---------------- row-wise RMSNorm: f32 in -> bf16 out ----------------
__global__ __launch_bounds__(256) void rmsnorm_kernel(const float* __restrict__ in,
                                                      const float* __restrict__ w,
                                                      unsigned short* __restrict__ out,
                                                      int ncols, int in_stride, int out_stride) {
  const int row = blockIdx.x;
  const float* rp = in + (size_t)row * in_stride;
  const int n4 = ncols >> 2;
  float4 v[2];
  int nv = 0;
  float ss = 0.f;
  for (int c = threadIdx.x; c < n4; c += 256) {
    float4 xv = reinterpret_cast<const float4*>(rp)[c];
    v[nv++] = xv;
    ss += xv.x * xv.x + xv.y * xv.y + xv.z * xv.z + xv.w * xv.w;
  }
#pragma unroll
  for (int m = 32; m; m >>= 1) ss += __shfl_xor(ss, m);
  __shared__ float red[4];
  if ((threadIdx.x & 63) == 0) red[threadIdx.x >> 6] = ss;
  __syncthreads();
  const float total = red[0] + red[1] + red[2] + red[3];
  const float scale = rsqrtf(total / (float)ncols + 1e-6f);
  nv = 0;
  unsigned short* op = out + (size_t)row * out_stride;
  for (int c = threadIdx.x; c < n4; c += 256) {
    float4 xv = v[nv++];
    float4 wv = reinterpret_cast<const float4*>(w)[c];
    u16x4 o;
    o[0] = f2b(xv.x * scale * wv.x);
    o[1] = f2b(xv.y * scale * wv.y);
    o[2] = f2b(xv.z * scale * wv.z);
    o[3] = f2b(xv.w * scale * wv.w);
    reinterpret_cast<u16x4*>(op)[c] = o;
  }
}

// ---------------- row-wise RMSNorm: bf16 in -> bf16 out (f32 math) ----------------
__global__ __launch_bounds__(256) void rmsnorm_b16(const unsigned short* __restrict__ in,
                                                   const float* __restrict__ w,
                                                   unsigned short* __restrict__ out,
                                                   int ncols) {
  const int row = blockIdx.x;
  const unsigned short* rp = in + (size_t)row * ncols;
  const int n4 = ncols >> 2;
  float4 v[2];
  int nv = 0;
  float ss = 0.f;
  for (int c = threadIdx.x; c < n4; c += 256) {
    u16x4 xb = reinterpret_cast<const u16x4*>(rp)[c];
    float4 xv = make_float4(b2f(xb[0]), b2f(xb[1]), b2f(xb[2]), b2f(xb[3]));
    v[nv++] = xv;
    ss += xv.x * xv.x + xv.y * xv.y + xv.z * xv.z + xv.w * xv.w;
  }
#pragma unroll
  for (int m = 32; m; m >>= 1) ss += __shfl_xor(ss, m);
  __shared__ float red[4];
  if ((threadIdx.x & 63) == 0) red[threadIdx.x >> 6] = ss;
  __syncthreads();
  const float total = red[0] + red[1] + red[2] + red[3];
  const float scale = rsqrtf(total / (float)ncols + 1e-6f);
  nv = 0;
  unsigned short* op = out + (size_t)row * ncols;
  for (int c = threadIdx.x; c < n4; c += 256) {
    float4 xv = v[nv++];
    float4 wv = reinterpret_cast<const float4*>(w)[c];
    u16x4 o;
    o[0] = f2b(xv.x * scale * wv.x);
    o[1] = f2b(xv.y * scale * wv.y);
    o[2] = f2b(xv.z * scale * wv.z);
    o[3] = f2b(xv.w * scale * wv.w);
    reinterpret_cast<u16x4*>(op)[c] = o;
  }
}

// ---------------- GEMM small-N fallback: m97 structure (used for N=576) ----------------
template <int EPI>
__global__ __launch_bounds__(256) void gemm_bt(const unsigned short* __restrict__ A,
                                               const unsigned short* __restrict__ Bt,
                                               float* __restrict__ outf,
                                               unsigned short* __restrict__ outb,
                                               const float* __restrict__ res,
                                               const unsigned short* __restrict__ aux,
                                               int M, int N, int K) {
  __shared__ __align__(16) unsigned short As[128 * 32];
  __shared__ __align__(16) unsigned short Bs[128 * 32];
  const int tid = threadIdx.x;
  const int l = tid & 63;
  const int lr = l & 15, lg = l >> 4;
  const int wr = tid >> 7, wc = (tid >> 6) & 1;

  const int gx = gridDim.x;
  const int nwg = gx * gridDim.y;
  int lin = blockIdx.y * gx + blockIdx.x;
  {
    const int qq = nwg >> 3, rr = nwg & 7;
    const int xcd = lin & 7, idx = lin >> 3;
    lin = (xcd < rr ? xcd * (qq + 1) : rr * (qq + 1) + (xcd - rr) * qq) + idx;
  }
  const int m0 = (lin / gx) * 128, n0 = (lin % gx) * 128;

  f32x4 acc[4][4] = {};

  for (int k0 = 0; k0 < K; k0 += 32) {
#pragma unroll
    for (int j = 0; j < 2; ++j) {
      const int chunk = j * 256 + tid;
      const int row = chunk >> 2, kc = chunk & 3;
      const unsigned short* ga = A + (size_t)(m0 + row) * K + k0 + kc * 8;
      gload_lds16(ga, &As[(size_t)(j * 256 + (tid & 192)) * 8]);
      int rb = n0 + row;
      if (rb > N - 1) rb = N - 1;
      const unsigned short* gb = Bt + (size_t)rb * K + k0 + kc * 8;
      gload_lds16(gb, &Bs[(size_t)(j * 256 + (tid & 192)) * 8]);
    }
    __syncthreads();
    bf16x8 af[4], bfr[4];
#pragma unroll
    for (int mi = 0; mi < 4; ++mi)
      af[mi] = *reinterpret_cast<const bf16x8*>(&As[(wr * 64 + mi * 16 + lr) * 32 + lg * 8]);
#pragma unroll
    for (int ni = 0; ni < 4; ++ni)
      bfr[ni] = *reinterpret_cast<const bf16x8*>(&Bs[(wc * 64 + ni * 16 + lr) * 32 + lg * 8]);
#pragma unroll
    for (int mi = 0; mi < 4; ++mi)
#pragma unroll
      for (int ni = 0; ni < 4; ++ni)
        acc[mi][ni] = __builtin_amdgcn_mfma_f32_16x16x32_bf16(af[mi], bfr[ni], acc[mi][ni], 0, 0, 0);
    __syncthreads();
  }

#pragma unroll
  for (int mi = 0; mi < 4; ++mi) {
#pragma unroll
    for (int ni = 0; ni < 4; ++ni) {
      const int r0 = m0 + wr * 64 + mi * 16 + lg * 4;
      const int c = n0 + wc * 64 + ni * 16 + lr;
      if (c < N) {
#pragma unroll
        for (int j = 0; j < 4; ++j) {
          const size_t idx = (size_t)(r0 + j) * N + c;
          const float v = acc[mi][ni][j];
          if constexpr (EPI == 0) outf[idx] = v;
          else if constexpr (EPI == 1) outb[idx] = f2b(v);
          else if constexpr (EPI == 2) outf[idx] = v + res[idx];
          else if constexpr (EPI == 3) outb[idx] = f2b(v / (1.f + __expf(-v)));
          else outb[idx] = f2b(v * b2f(aux[idx]));
        }
      }
    }
  }
}

// ---------------- GEMM 256x256 (r11/r14-validated): quadrant 8-phase, compiler lgkmcnt ----------------
// EPI 5: fused gate/up — Bt interleaved (per 256-row block: 128 gate | 128 up);
// qc=0 quadrants hold gate acc, qc=1 up acc; epilogue writes silu(g)*u to outb[.][N/2].
template <int EPI>
__global__ __launch_bounds__(512, 1) void gemm256(const unsigned short* __restrict__ A,
                                                  const unsigned short* __restrict__ Bt,
                                                  float* __restrict__ outf,
                                                  unsigned short* __restrict__ outb,
                                                  const float* __restrict__ res,
                                                  const unsigned short* __restrict__ aux,
                                                  int M, int N, int K) {
  __shared__ __align__(16) unsigned short Lds[2][2][2][128 * 64];
  const int tid = threadIdx.x;
  const int l = tid & 63, lr = l & 15, lg = l >> 4;
  const int w = tid >> 6, swr = w >> 2, swn = w & 3;   // 2x4 waves inside a quadrant

  const int gn = N >> 8;
  int lin = blockIdx.x;
  {
    const int nwg = gridDim.x;
    lin = (lin & 7) * (nwg >> 3) + (lin >> 3);   // XCD chunking (nwg%8==0)
  }
  const int npg = gn << 3;
  const int gid = lin / npg;
  const int idx = lin - gid * npg;
  const int m0 = (gid * 8 + (idx & 7)) * 256;
  const int n0 = (idx >> 3) * 256;

  const int NT = K >> 6;

  f32x4 acc[4][8] = {};   // [quadrant][fi*2+fj]

  // stage one half-tile (16KB): mat 0=A/1=B, rowhalf rh, K-tile t -> dbuf t&1
  auto stageh = [&](int mat, int rh, int t) {
    const unsigned short* src = mat ? Bt : A;
    const int rbase = (mat ? n0 : m0) + rh * 128;
    const int d = t & 1;
#pragma unroll
    for (int g = 0; g < 2; ++g) {
      const int c = g * 512 + tid;
      const int row = c >> 3;                 // 0..127
      const int kc = (c & 7) ^ (row & 7);     // pre-swizzled global source chunk
      gload_lds16(src + (size_t)(rbase + row) * K + t * 64 + kc * 8,
                  &Lds[d][mat][rh][(size_t)(g * 512 + (tid & ~63)) * 8]);
    }
  };

  // prologue: tile 0 fully + A0,B0 of tile 1
  stageh(0, 0, 0); stageh(1, 0, 0); stageh(0, 1, 0); stageh(1, 1, 0);
  if (NT > 1) {
    stageh(0, 0, 1); stageh(1, 0, 1);
    asm volatile("s_waitcnt vmcnt(4)" ::: "memory");
  } else {
    asm volatile("s_waitcnt vmcnt(0)" ::: "memory");
  }
  __builtin_amdgcn_s_barrier();
  __builtin_amdgcn_sched_barrier(0);

#define RD_A(qr, fi, kk)                                                                    \
  af[fi][kk] = *reinterpret_cast<const bf16x8*>(                                            \
      &Lds[d][0][qr][(swr * 64 + (fi) * 16 + lr) * 64 + (((kk) * 4 + lg) ^ (lr & 7)) * 8])
#define RD_B(qc, fj, kk)                                                                    \
  bfv[fj][kk] = *reinterpret_cast<const bf16x8*>(                                           \
      &Lds[d][1][qc][(swn * 32 + (fj) * 16 + lr) * 64 + (((kk) * 4 + lg) ^ (lr & 7)) * 8])
#define MFMAQ(q)                                                                            \
  _Pragma("unroll") for (int fi = 0; fi < 4; ++fi)                                          \
  _Pragma("unroll") for (int fj = 0; fj < 2; ++fj)                                          \
  _Pragma("unroll") for (int kk = 0; kk < 2; ++kk)                                          \
      acc[q][fi * 2 + fj] =                                                                 \
          __builtin_amdgcn_mfma_f32_16x16x32_bf16(af[fi][kk], bfv[fj][kk], acc[q][fi * 2 + fj], 0, 0, 0)

  for (int T = 0; T < NT; ++T) {
    const int d = T & 1;
    bf16x8 af[4][2], bfv[2][2];

    // ---- ph1: q=(0,0) — read A-rh0 (8) + B-rh0 (4); stage A-rh1(T+1); W2
    RD_A(0, 0, 0); RD_A(0, 0, 1); RD_A(0, 1, 0); RD_A(0, 1, 1);
    RD_A(0, 2, 0); RD_A(0, 2, 1); RD_A(0, 3, 0); RD_A(0, 3, 1);
    RD_B(0, 0, 0); RD_B(0, 0, 1); RD_B(0, 1, 0); RD_B(0, 1, 1);
    if (T + 1 < NT) stageh(0, 1, T + 1);
    __builtin_amdgcn_s_setprio(1);
    MFMAQ(0);
    __builtin_amdgcn_s_setprio(0);
    if (T + 1 < NT) asm volatile("s_waitcnt vmcnt(6)" ::: "memory");   // W2
    else            asm volatile("s_waitcnt vmcnt(0)" ::: "memory");
    __builtin_amdgcn_s_barrier();
    __builtin_amdgcn_sched_barrier(0);

    // ---- ph2: q=(0,1) — read B-rh1 (4, A reused); stage B-rh1(T+1)
    RD_B(1, 0, 0); RD_B(1, 0, 1); RD_B(1, 1, 0); RD_B(1, 1, 1);
    if (T + 1 < NT) stageh(1, 1, T + 1);
    __builtin_amdgcn_s_setprio(1);
    MFMAQ(1);
    __builtin_amdgcn_s_setprio(0);
    __builtin_amdgcn_s_barrier();
    __builtin_amdgcn_sched_barrier(0);

    // ---- ph3: q=(1,0) — read A-rh1 (8) + B-rh0 (4); stage A-rh0(T+2)
    RD_A(1, 0, 0); RD_A(1, 0, 1); RD_A(1, 1, 0); RD_A(1, 1, 1);
    RD_A(1, 2, 0); RD_A(1, 2, 1); RD_A(1, 3, 0); RD_A(1, 3, 1);
    RD_B(0, 0, 0); RD_B(0, 0, 1); RD_B(0, 1, 0); RD_B(0, 1, 1);
    if (T + 2 < NT) stageh(0, 0, T + 2);
    __builtin_amdgcn_s_setprio(1);
    MFMAQ(2);
    __builtin_amdgcn_s_setprio(0);
    __builtin_amdgcn_s_barrier();
    __builtin_amdgcn_sched_barrier(0);

    // ---- ph4: q=(1,1) — read B-rh1 (4, A reused); stage B-rh0(T+2); W1
    RD_B(1, 0, 0); RD_B(1, 0, 1); RD_B(1, 1, 0); RD_B(1, 1, 1);
    if (T + 2 < NT) stageh(1, 0, T + 2);
    __builtin_amdgcn_s_setprio(1);
    MFMAQ(3);
    __builtin_amdgcn_s_setprio(0);
    if (T + 2 < NT)      asm volatile("s_waitcnt vmcnt(8)" ::: "memory");  // W1
    else if (T + 1 < NT) asm volatile("s_waitcnt vmcnt(4)" ::: "memory");
    __builtin_amdgcn_s_barrier();
    __builtin_amdgcn_sched_barrier(0);
  }

#undef RD_A
#undef RD_B
#undef MFMAQ

  if constexpr (EPI == 5) {
    // fused gate/up: act[r][(n0>>1)+...] = silu(gate) * up; act stride = N/2
    const int actN = N >> 1;
#pragma unroll
    for (int qr = 0; qr < 2; ++qr) {
#pragma unroll
      for (int fi = 0; fi < 4; ++fi) {
#pragma unroll
        for (int fj = 0; fj < 2; ++fj) {
          const int r0 = m0 + qr * 128 + swr * 64 + fi * 16 + lg * 4;
          const int cA = (n0 >> 1) + swn * 32 + fj * 16 + lr;
#pragma unroll
          for (int j = 0; j < 4; ++j) {
            const float g = acc[qr * 2][fi * 2 + fj][j];
            const float u = acc[qr * 2 + 1][fi * 2 + fj][j];
            outb[(size_t)(r0 + j) * actN + cA] = f2b(g / (1.f + __expf(-g)) * u);
          }
        }
      }
    }
  } else {
#pragma unroll
    for (int q = 0; q < 4; ++q) {
      const int qr = q >> 1, qc = q & 1;
#pragma unroll
      for (int fi = 0; fi < 4; ++fi) {
#pragma unroll
        for (int fj = 0; fj < 2; ++fj) {
          const int r = m0 + qr * 128 + swr * 64 + fi * 16 + lg * 4;
          const int c = n0 + qc * 128 + swn * 32 + fj * 16 + lr;
#pragma unroll
          for (int j = 0; j < 4; ++j) {
            const size_t idx2 = (size_t)(r + j) * N + c;
            const float v = acc[q][fi * 2 + fj][j];
            if constexpr (EPI == 0) outf[idx2] = v;
            else if constexpr (EPI == 1) outb[idx2] = f2b(v);
            else if constexpr (EPI == 2) outf[idx2] = v + res[idx2];
            else if constexpr (EPI == 3) outb[idx2] = f2b(v / (1.f + __expf(-v)));
            else if constexpr (EPI == 4) outb[idx2] = f2b(v * b2f(aux[idx2]));
          }
        }
      }
    }
  }
}

// ---------------- RoPE on q rope-dims only (scale folded into wq_b) ----------------
__global__ __launch_bounds__(256) void rope_q(unsigned short* __restrict__ q,
                                              const int* __restrict__ positions) {
  const int row = blockIdx.x;
  const int pos = positions[row];
  unsigned short* qp = q + (size_t)row * 3072;
  const int tid = threadIdx.x;
#pragma unroll
  for (int i = 0; i < 2; ++i) {           // 16 heads x 32 pairs
    int e = i * 256 + tid;
    int hh = e >> 5, j = e & 31;
    int base = hh * 192 + 128;
    float x1 = b2f(qp[base + j]), x2 = b2f(qp[base + 32 + j]);
    float freq = __expf(-(float)j * (9.210340371976184f / 32.f));  // 10000^(-j/32)
    float sa, ca;
    __sincosf((float)pos * freq, &sa, &ca);
    qp[base + j] = f2b(x1 * ca - x2 * sa);
    qp[base + 32 + j] = f2b(x2 * ca + x1 * sa);
  }
}

// ---- build kh [B*T,16,192]: k_pass from kv[...,0:128], roped k_rot broadcast ----
__global__ __launch_bounds__(256) void repack_k(const unsigned short* __restrict__ kv,
                                                const float* __restrict__ ckv,
                                                const int* __restrict__ positions,
                                                unsigned short* __restrict__ kh) {
  const int row = blockIdx.x;
  const int tid = threadIdx.x;
  {
    const int hh = tid >> 4, db = tid & 15;
    u16x8 v = *reinterpret_cast<const u16x8*>(kv + (size_t)row * 4096 + hh * 256 + db * 8);
    *reinterpret_cast<u16x8*>(kh + (size_t)row * 3072 + hh * 192 + db * 8) = v;
  }
  __shared__ float o1[32], o2[32];
  if (tid < 32) {
    const int j = tid;
    float x1 = ckv[(size_t)row * 576 + 512 + j];
    float x2 = ckv[(size_t)row * 576 + 544 + j];
    const int pos = positions[row];
    float freq = __expf(-(float)j * (9.210340371976184f / 32.f));
    float sa, ca;
    __sincosf((float)pos * freq, &sa, &ca);
    o1[j] = x1 * ca - x2 * sa;
    o2[j] = x2 * ca + x1 * sa;
  }
  __syncthreads();
  // 16 heads x 64 dims, 4 contiguous dims per thread (u16x4 store)
  {
    const int hh = tid >> 4, dg = (tid & 15) * 4;
    u16x4 o;
#pragma unroll
    for (int j = 0; j < 4; ++j) {
      const int d = dg + j;
      o[j] = f2b((d < 32) ? o1[d] : o2[d - 32]);
    }
    *reinterpret_cast<u16x4*>(&kh[(size_t)row * 3072 + hh * 192 + 128 + dg]) = o;
  }
}

// ---- flash attention v5: QBLK=128, 8 waves, defer-max + ones-MFMA, qt-paired balance ----
__global__ __launch_bounds__(512) void mla_attn(const unsigned short* __restrict__ qh,  // [B*T][16][192]
                                                const unsigned short* __restrict__ kh,  // [B*T][16][192]
                                                const unsigned short* __restrict__ kv,  // [B*T][16][256]
                                                unsigned short* __restrict__ o) {       // [B*T][2048]
  const int T = 2048, H = 16;
  const int bx = blockIdx.x;            // 0..7
  const int b = blockIdx.y >> 4;
  const int h = blockIdx.y & 15;
  const int tid = threadIdx.x, w = tid >> 6, l = tid & 63;
  const int lg = l >> 4, lr = l & 15;

  __shared__ __align__(16) unsigned short Ks[64 * 200];
  __shared__ __align__(16) unsigned short Vts[128 * 64];   // block-swizzled
  __shared__ __align__(16) unsigned short Pl[8][16 * 72];
  __shared__ float exs[8][16];

  int krow[3], kcol[3];
#pragma unroll
  for (int i = 0; i < 3; ++i) { int c = i * 512 + tid; krow[i] = c / 24; kcol[i] = (c % 24) * 8; }
  const int vkvp = tid >> 4;          // 0..31 (pairs of kv rows)
  const int vf0 = (tid & 15) * 8;     // feature chunk

  const unsigned short* kbase0 = kh + (((size_t)b * T) * H + h) * 192;       // +t*3072
  const unsigned short* vbase0 = kv + (((size_t)b * T) * H + h) * 256 + 128; // +t*4096

  bf16x8 ones;
#pragma unroll
  for (int e = 0; e < 8; ++e) ones[e] = (__bf16)1.0f;

  for (int half = 0; half < 2; ++half) {
    const int qt = half ? (15 - bx) : bx;

    bf16x8 qa[6];
    {
      const size_t qrow = (size_t)b * T + qt * 128 + w * 16 + lr;
      const unsigned short* qp = qh + (qrow * H + h) * 192 + lg * 8;
#pragma unroll
      for (int kc = 0; kc < 6; ++kc)
        qa[kc] = *reinterpret_cast<const bf16x8*>(qp + kc * 32);
    }

    u16x8 kreg[3], vregA, vregB;
#pragma unroll
    for (int i = 0; i < 3; ++i)
      kreg[i] = *reinterpret_cast<const u16x8*>(kbase0 + (size_t)krow[i] * 3072 + kcol[i]);
    vregA = *reinterpret_cast<const u16x8*>(vbase0 + (size_t)(2 * vkvp) * 4096 + vf0);
    vregB = *reinterpret_cast<const u16x8*>(vbase0 + (size_t)(2 * vkvp + 1) * 4096 + vf0);

    f32x4 ot[8] = {};
    f32x4 lacc = {};
    float mrow[4] = {NEG_BIG, NEG_BIG, NEG_BIG, NEG_BIG};

    const int ktmax = 2 * qt + 1;
    for (int kt = 0; kt <= ktmax; ++kt) {
#pragma unroll
      for (int i = 0; i < 3; ++i)
        *reinterpret_cast<u16x8*>(&Ks[krow[i] * 200 + kcol[i]]) = kreg[i];
      {
        const int c7 = (vf0 >> 3) & 7;
#pragma unroll
        for (int e = 0; e < 8; ++e) {
          const int blk = (vkvp >> 2) ^ (e ^ c7);
          const unsigned val = (unsigned)(unsigned short)vregA[e] |
                               ((unsigned)(unsigned short)vregB[e] << 16);
          *reinterpret_cast<unsigned*>(&Vts[(vf0 + e) * 64 + blk * 8 + (vkvp & 3) * 2]) = val;
        }
      }
      __syncthreads();

      if (kt < ktmax) {
        const unsigned short* kb = kbase0 + (size_t)(kt + 1) * 64 * 3072;
        const unsigned short* vb = vbase0 + (size_t)(kt + 1) * 64 * 4096;
#pragma unroll
        for (int i = 0; i < 3; ++i)
          kreg[i] = *reinterpret_cast<const u16x8*>(kb + (size_t)krow[i] * 3072 + kcol[i]);
        vregA = *reinterpret_cast<const u16x8*>(vb + (size_t)(2 * vkvp) * 4096 + vf0);
        vregB = *reinterpret_cast<const u16x8*>(vb + (size_t)(2 * vkvp + 1) * 4096 + vf0);
      }

      f32x4 s4[4];
#pragma unroll
      for (int ni = 0; ni < 4; ++ni) {
        f32x4 a = {};
#pragma unroll
        for (int kc = 0; kc < 6; ++kc) {
          bf16x8 kf = *reinterpret_cast<const bf16x8*>(&Ks[(ni * 16 + lr) * 200 + kc * 32 + lg * 8]);
          a = __builtin_amdgcn_mfma_f32_16x16x32_bf16(qa[kc], kf, a, 0, 0, 0);
        }
        s4[ni] = a;
      }
      if (kt >= 2 * qt) {
#pragma unroll
        for (int ni = 0; ni < 4; ++ni) {
          const int colr = ni * 16 + lr;
#pragma unroll
          for (int j = 0; j < 4; ++j) {
            const int qrl = qt * 128 + w * 16 + lg * 4 + j - kt * 64;
            if (colr > qrl) s4[ni][j] = NEG_BIG;
          }
        }
      }

      // T13 defer-max
      float pmj[4];
      int need = 0;
#pragma unroll
      for (int j = 0; j < 4; ++j) {
        pmj[j] = fmaxf(fmaxf(s4[0][j], s4[1][j]), fmaxf(s4[2][j], s4[3][j]));
        need |= (pmj[j] > mrow[j] + 8.f) ? 1 : 0;
      }
      if (__any(need)) {
        float al[4];
#pragma unroll
        for (int j = 0; j < 4; ++j) {
          float rm = pmj[j];
#pragma unroll
          for (int m = 1; m < 16; m <<= 1) rm = fmaxf(rm, __shfl_xor(rm, m));
          const float mn = fmaxf(mrow[j], rm);
          al[j] = __expf(mrow[j] - mn);
          mrow[j] = mn;
        }
        if (lr == 0) {
#pragma unroll
          for (int j = 0; j < 4; ++j) exs[w][lg * 4 + j] = al[j];
        }
        const float af = exs[w][lr];
#pragma unroll
        for (int mi = 0; mi < 8; ++mi) {
          ot[mi][0] *= af; ot[mi][1] *= af; ot[mi][2] *= af; ot[mi][3] *= af;
        }
        lacc[0] *= af; lacc[1] *= af; lacc[2] *= af; lacc[3] *= af;
      }

#pragma unroll
      for (int ni = 0; ni < 4; ++ni)
#pragma unroll
        for (int j = 0; j < 4; ++j)
          Pl[w][(lg * 4 + j) * 72 + ni * 16 + lr] = f2b(__expf(s4[ni][j] - mrow[j]));

      bf16x8 pf0 = *reinterpret_cast<const bf16x8*>(&Pl[w][lr * 72 + lg * 8]);
      bf16x8 pf1 = *reinterpret_cast<const bf16x8*>(&Pl[w][lr * 72 + 32 + lg * 8]);
      lacc = __builtin_amdgcn_mfma_f32_16x16x32_bf16(ones, pf0, lacc, 0, 0, 0);
      lacc = __builtin_amdgcn_mfma_f32_16x16x32_bf16(ones, pf1, lacc, 0, 0, 0);
#pragma unroll
      for (int mi = 0; mi < 8; ++mi) {
        const int f = mi * 16 + lr;
        const int sfz = (f & 7) ^ ((f >> 3) & 7);
        const int blk0 = lg ^ sfz;
        const int blk1 = (4 + lg) ^ sfz;
        bf16x8 vf0r = *reinterpret_cast<const bf16x8*>(&Vts[f * 64 + blk0 * 8]);
        ot[mi] = __builtin_amdgcn_mfma_f32_16x16x32_bf16(vf0r, pf0, ot[mi], 0, 0, 0);
        bf16x8 vf1r = *reinterpret_cast<const bf16x8*>(&Vts[f * 64 + blk1 * 8]);
        ot[mi] = __builtin_amdgcn_mfma_f32_16x16x32_bf16(vf1r, pf1, ot[mi], 0, 0, 0);
      }
      __syncthreads();
    }

    const float li = 1.f / lacc[0];
    const size_t orow = (size_t)b * T + qt * 128 + w * 16 + lr;
#pragma unroll
    for (int mi = 0; mi < 8; ++mi)
#pragma unroll
      for (int j = 0; j < 4; ++j) {
        const int feat = mi * 16 + lg * 4 + j;
        o[orow * 2048 + h * 128 + feat] = f2b(ot[mi][j] * li);
      }
  }
}

// ---------------- host ----------------
extern "C" void kernel_launch(void* const* d_in, const int* in_sizes, int n_in,
                              void* d_out, int out_size, void* d_ws, size_t ws_size,
                              hipStream_t stream) {
  (void)in_sizes; (void)n_in;
  const float* x      = (const float*)d_in[0];
  const float* ln1_w  = (const float*)d_in[1];
  const float* wq_a   = (const float*)d_in[2];
  const float* qaln_w = (const float*)d_in[3];
  const float* wq_b   = (const float*)d_in[4];
  const float* wkv_a  = (const float*)d_in[5];
  const float* kvln_w = (const float*)d_in[6];
  const float* wkv_b  = (const float*)d_in[7];
  const float* wo     = (const float*)d_in[8];
  const float* ln2_w  = (const float*)d_in[9];
  const float* w_gate = (const float*)d_in[10];
  const float* w_up   = (const float*)d_in[11];
  const float* w_down = (const float*)d_in[12];
  const int*   pos    = (const int*)d_in[14];
  float* out = (float*)d_out;

  const int Mt = 8192;  // B*T

  char* ws = (char*)d_ws;
  const size_t R1 = 0;                          // qa_b16 -> kvbuf
  const size_t R2 = R1 + 67108864;              // qbuf
  const size_t R3 = R2 + 50331648;              // qan -> ckvn -> khbuf
  const size_t R4 = R3 + 50331648;              // hbuf -> obuf
  const size_t R5 = R4 + 33554432;              // ckv (f32)
  const size_t R6 = R5 + 18874368;              // weight slot (9.4MB)
  const size_t REQ = R6 + 9437184;              // 229,638,144 total

  if (ws_size < REQ) {
    fill_sentinel<<<dim3((out_size + 255) / 256), dim3(256), 0, stream>>>(
        out, out_size, (float)(ws_size >> 20));
    return;
  }

  unsigned short* qa_b16 = (unsigned short*)(ws + R1);
  unsigned short* kvbuf  = (unsigned short*)(ws + R1);
  unsigned short* qbuf   = (unsigned short*)(ws + R2);
  unsigned short* qan    = (unsigned short*)(ws + R3);
  unsigned short* ckvn   = (unsigned short*)(ws + R3);
  unsigned short* khbuf  = (unsigned short*)(ws + R3);
  unsigned short* hbuf   = (unsigned short*)(ws + R4);
  unsigned short* obuf   = (unsigned short*)(ws + R4);
  float*          ckv    = (float*)(ws + R5);
  unsigned short* slotW  = (unsigned short*)(ws + R6);
  // MLP-phase overlay (all attention-phase buffers dead by then):
  unsigned short* actb  = (unsigned short*)(ws + 0);           // act half: 8192x4096 bf16 = 64MB
  unsigned short* h2b   = (unsigned short*)(ws + 134217728);   // 32MB
  unsigned short* wsl2  = (unsigned short*)(ws + 167772160);   // interleaved W: 8192x2048 bf16 = 32MB

  dim3 blk(256);
  dim3 blk5(512);
  auto tcf = [&](const float* W, int K, int N, float scale) {
    transpose_convert<<<dim3((N + 31) / 32, (K + 31) / 32), blk, 0, stream>>>(W, slotW, K, N, N, 0, 0, scale, -1);
  };
  auto g256 = [&](auto epi, const unsigned short* Aa, const unsigned short* Bb, float* of,
                  unsigned short* ob, const float* rs, const unsigned short* ax, int N, int K) {
    gemm256<decltype(epi)::value><<<dim3(32 * (N >> 8)), blk5, 0, stream>>>(Aa, Bb, of, ob, rs, ax, Mt, N, K);
  };

  // h = rmsnorm(x)
  rmsnorm_kernel<<<Mt, blk, 0, stream>>>(x, ln1_w, hbuf, 2048, 2048, 2048);
  // q_a = h @ wq_a (bf16) ; rmsnorm(bf16) -> qan
  tcf(wq_a, 2048, 1536, 1.0f);
  g256(std::integral_constant<int,1>{}, hbuf, slotW, nullptr, qa_b16, nullptr, nullptr, 1536, 2048);
  rmsnorm_b16<<<Mt, blk, 0, stream>>>(qa_b16, qaln_w, qan, 1536);
  // q = qan @ (wq_b * SCALE) (bf16)
  tcf(wq_b, 1536, 3072, 0.07216878364870322f);
  g256(std::integral_constant<int,1>{}, qan, slotW, nullptr, qbuf, nullptr, nullptr, 3072, 1536);
  // ckv = h @ wkv_a (f32, N=576 -> m97 path) ; rmsnorm(k_c) -> ckvn
  tcf(wkv_a, 2048, 576, 1.0f);
  gemm_bt<0><<<dim3(5, 64), blk, 0, stream>>>(hbuf, slotW, ckv, nullptr, nullptr, nullptr, Mt, 576, 2048);
  rmsnorm_kernel<<<Mt, blk, 0, stream>>>(ckv, kvln_w, ckvn, 512, 576, 512);
  // kv = ckvn @ wkv_b (bf16)
  tcf(wkv_b, 512, 4096, 1.0f);
  g256(std::integral_constant<int,1>{}, ckvn, slotW, nullptr, kvbuf, nullptr, nullptr, 4096, 512);
  // rope q (rope dims only); build kh
  rope_q<<<Mt, blk, 0, stream>>>(qbuf, pos);
  repack_k<<<Mt, blk, 0, stream>>>(kvbuf, ckv, pos, khbuf);
  // attention -> obuf   (qt-paired: grid 8 x 64, 512 threads, uniform 34 tiles/block)
  mla_attn<<<dim3(8, 64), blk5, 0, stream>>>(qbuf, khbuf, kvbuf, obuf);
  // x1 = x + o @ wo   (x1 lives in d_out)
  tcf(wo, 2048, 2048, 1.0f);
  g256(std::integral_constant<int,2>{}, obuf, slotW, out, nullptr, x, nullptr, 2048, 2048);
  // h2 = rmsnorm(x1)
  rmsnorm_kernel<<<Mt, blk, 0, stream>>>(out, ln2_w, h2b, 2048, 2048, 2048);
  // MLP in 2 halves of D_FF=4096, fused gate/up (interleaved weights, EPI=5):
  //   act = silu(h2@Wg_c) * (h2@Wu_c); out += act @ Wd_c
  for (int c = 0; c < 2; ++c) {
    transpose_convert<<<dim3(128, 64), blk, 0, stream>>>(w_gate, wsl2, 2048, 4096, 8192, 0, c * 4096, 1.0f, 0);
    transpose_convert<<<dim3(128, 64), blk, 0, stream>>>(w_up,   wsl2, 2048, 4096, 8192, 0, c * 4096, 1.0f, 128);
    g256(std::integral_constant<int,5>{}, h2b, wsl2, nullptr, actb, nullptr, nullptr, 8192, 2048);
    transpose_convert<<<dim3(64, 128), blk, 0, stream>>>(w_down, wsl2, 4096, 2048, 2048, c * 4096, 0, 1.0f, -1);
    g256(std::integral_constant<int,2>{}, actb, wsl2, out, nullptr, out, nullptr, 2048, 4096);
  }
}

// Round 20
// 1456.401 us; speedup vs baseline: 1.0277x; 1.0277x over previous
//
#include <hip/hip_runtime.h>

// ---------------- types / helpers ----------------
typedef float f32x4 __attribute__((ext_vector_type(4)));
typedef __bf16 bf16x8 __attribute__((ext_vector_type(8)));
typedef unsigned short u16x8 __attribute__((ext_vector_type(8)));
typedef unsigned short u16x4 __attribute__((ext_vector_type(4)));

static __device__ __forceinline__ unsigned short f2b(float f) {
  union { float f; unsigned u; } v; v.f = f;
  unsigned r = v.u + 0x7fffu + ((v.u >> 16) & 1u);   // RNE
  return (unsigned short)(r >> 16);
}
static __device__ __forceinline__ float b2f(unsigned short s) {
  union { unsigned u; float f; } v; v.u = ((unsigned)s) << 16;
  return v.f;
}
static __device__ __forceinline__ void gload_lds16(const unsigned short* g, unsigned short* l) {
  __builtin_amdgcn_global_load_lds((const __attribute__((address_space(1))) void*)g,
                                   (__attribute__((address_space(3))) void*)l, 16, 0, 0);
}

#define NEG_BIG -3.0e38f

// ---------------- ws-too-small sentinel ----------------
__global__ __launch_bounds__(256) void fill_sentinel(float* __restrict__ out, int n, float v) {
  int i = blockIdx.x * 256 + threadIdx.x;
  if (i < n) out[i] = v;
}

// -------- transpose + fp32->bf16 (+scale): out[orow*K+k] = in[(row0+k)*in_ld + col0+n]*scale
// ilv_off < 0: orow = n (linear).  ilv_off >= 0: orow = ((n>>7)<<8) + (n&127) + ilv_off
// (gate/up interleave: 128-col groups packed into 256-row blocks). --------
__global__ __launch_bounds__(256) void transpose_convert(const float* __restrict__ in,
                                                         unsigned short* __restrict__ out,
                                                         int K, int N, int in_ld, int row0, int col0,
                                                         float scale, int ilv_off) {
  __shared__ float tile[32][33];
  const int k0 = blockIdx.y * 32, n0 = blockIdx.x * 32;
  const int tx = threadIdx.x & 31, ty = threadIdx.x >> 5;  // 32 x 8
#pragma unroll
  for (int i = 0; i < 32; i += 8) {
    int k = k0 + ty + i, n = n0 + tx;
    tile[ty + i][tx] = (k < K && n < N) ? in[(size_t)(row0 + k) * in_ld + col0 + n] : 0.f;
  }
  __syncthreads();
#pragma unroll
  for (int i = 0; i < 32; i += 8) {
    int n = n0 + ty + i, k = k0 + tx;
    if (n < N && k < K) {
      const int orow = (ilv_off >= 0) ? (((n >> 7) << 8) + (n & 127) + ilv_off) : n;
      out[(size_t)orow * K + k] = f2b(tile[tx][ty + i] * scale);
    }
  }
}

// ---------------- row-wise RMSNorm: f32 in -> bf16 out ----------------
__global__ __launch_bounds__(256) void rmsnorm_kernel(const float* __restrict__ in,
                                                      const float* __restrict__ w,
                                                      unsigned short* __restrict__ out,
                                                      int ncols, int in_stride, int out_stride) {
  const int row = blockIdx.x;
  const float* rp = in + (size_t)row * in_stride;
  const int n4 = ncols >> 2;
  float4 v[2];
  int nv = 0;
  float ss = 0.f;
  for (int c = threadIdx.x; c < n4; c += 256) {
    float4 xv = reinterpret_cast<const float4*>(rp)[c];
    v[nv++] = xv;
    ss += xv.x * xv.x + xv.y * xv.y + xv.z * xv.z + xv.w * xv.w;
  }
#pragma unroll
  for (int m = 32; m; m >>= 1) ss += __shfl_xor(ss, m);
  __shared__ float red[4];
  if ((threadIdx.x & 63) == 0) red[threadIdx.x >> 6] = ss;
  __syncthreads();
  const float total = red[0] + red[1] + red[2] + red[3];
  const float scale = rsqrtf(total / (float)ncols + 1e-6f);
  nv = 0;
  unsigned short* op = out + (size_t)row * out_stride;
  for (int c = threadIdx.x; c < n4; c += 256) {
    float4 xv = v[nv++];
    float4 wv = reinterpret_cast<const float4*>(w)[c];
    u16x4 o;
    o[0] = f2b(xv.x * scale * wv.x);
    o[1] = f2b(xv.y * scale * wv.y);
    o[2] = f2b(xv.z * scale * wv.z);
    o[3] = f2b(xv.w * scale * wv.w);
    reinterpret_cast<u16x4*>(op)[c] = o;
  }
}

// ---------------- row-wise RMSNorm: bf16 in -> bf16 out (f32 math) ----------------
__global__ __launch_bounds__(256) void rmsnorm_b16(const unsigned short* __restrict__ in,
                                                   const float* __restrict__ w,
                                                   unsigned short* __restrict__ out,
                                                   int ncols) {
  const int row = blockIdx.x;
  const unsigned short* rp = in + (size_t)row * ncols;
  const int n4 = ncols >> 2;
  float4 v[2];
  int nv = 0;
  float ss = 0.f;
  for (int c = threadIdx.x; c < n4; c += 256) {
    u16x4 xb = reinterpret_cast<const u16x4*>(rp)[c];
    float4 xv = make_float4(b2f(xb[0]), b2f(xb[1]), b2f(xb[2]), b2f(xb[3]));
    v[nv++] = xv;
    ss += xv.x * xv.x + xv.y * xv.y + xv.z * xv.z + xv.w * xv.w;
  }
#pragma unroll
  for (int m = 32; m; m >>= 1) ss += __shfl_xor(ss, m);
  __shared__ float red[4];
  if ((threadIdx.x & 63) == 0) red[threadIdx.x >> 6] = ss;
  __syncthreads();
  const float total = red[0] + red[1] + red[2] + red[3];
  const float scale = rsqrtf(total / (float)ncols + 1e-6f);
  nv = 0;
  unsigned short* op = out + (size_t)row * ncols;
  for (int c = threadIdx.x; c < n4; c += 256) {
    float4 xv = v[nv++];
    float4 wv = reinterpret_cast<const float4*>(w)[c];
    u16x4 o;
    o[0] = f2b(xv.x * scale * wv.x);
    o[1] = f2b(xv.y * scale * wv.y);
    o[2] = f2b(xv.z * scale * wv.z);
    o[3] = f2b(xv.w * scale * wv.w);
    reinterpret_cast<u16x4*>(op)[c] = o;
  }
}

// ---------------- GEMM small-N fallback: m97 structure (used for N=576) ----------------
template <int EPI>
__global__ __launch_bounds__(256) void gemm_bt(const unsigned short* __restrict__ A,
                                               const unsigned short* __restrict__ Bt,
                                               float* __restrict__ outf,
                                               unsigned short* __restrict__ outb,
                                               const float* __restrict__ res,
                                               const unsigned short* __restrict__ aux,
                                               int M, int N, int K) {
  __shared__ __align__(16) unsigned short As[128 * 32];
  __shared__ __align__(16) unsigned short Bs[128 * 32];
  const int tid = threadIdx.x;
  const int l = tid & 63;
  const int lr = l & 15, lg = l >> 4;
  const int wr = tid >> 7, wc = (tid >> 6) & 1;

  const int gx = gridDim.x;
  const int nwg = gx * gridDim.y;
  int lin = blockIdx.y * gx + blockIdx.x;
  {
    const int qq = nwg >> 3, rr = nwg & 7;
    const int xcd = lin & 7, idx = lin >> 3;
    lin = (xcd < rr ? xcd * (qq + 1) : rr * (qq + 1) + (xcd - rr) * qq) + idx;
  }
  const int m0 = (lin / gx) * 128, n0 = (lin % gx) * 128;

  f32x4 acc[4][4] = {};

  for (int k0 = 0; k0 < K; k0 += 32) {
#pragma unroll
    for (int j = 0; j < 2; ++j) {
      const int chunk = j * 256 + tid;
      const int row = chunk >> 2, kc = chunk & 3;
      const unsigned short* ga = A + (size_t)(m0 + row) * K + k0 + kc * 8;
      gload_lds16(ga, &As[(size_t)(j * 256 + (tid & 192)) * 8]);
      int rb = n0 + row;
      if (rb > N - 1) rb = N - 1;
      const unsigned short* gb = Bt + (size_t)rb * K + k0 + kc * 8;
      gload_lds16(gb, &Bs[(size_t)(j * 256 + (tid & 192)) * 8]);
    }
    __syncthreads();
    bf16x8 af[4], bfr[4];
#pragma unroll
    for (int mi = 0; mi < 4; ++mi)
      af[mi] = *reinterpret_cast<const bf16x8*>(&As[(wr * 64 + mi * 16 + lr) * 32 + lg * 8]);
#pragma unroll
    for (int ni = 0; ni < 4; ++ni)
      bfr[ni] = *reinterpret_cast<const bf16x8*>(&Bs[(wc * 64 + ni * 16 + lr) * 32 + lg * 8]);
#pragma unroll
    for (int mi = 0; mi < 4; ++mi)
#pragma unroll
      for (int ni = 0; ni < 4; ++ni)
        acc[mi][ni] = __builtin_amdgcn_mfma_f32_16x16x32_bf16(af[mi], bfr[ni], acc[mi][ni], 0, 0, 0);
    __syncthreads();
  }

#pragma unroll
  for (int mi = 0; mi < 4; ++mi) {
#pragma unroll
    for (int ni = 0; ni < 4; ++ni) {
      const int r0 = m0 + wr * 64 + mi * 16 + lg * 4;
      const int c = n0 + wc * 64 + ni * 16 + lr;
      if (c < N) {
#pragma unroll
        for (int j = 0; j < 4; ++j) {
          const size_t idx = (size_t)(r0 + j) * N + c;
          const float v = acc[mi][ni][j];
          if constexpr (EPI == 0) outf[idx] = v;
          else if constexpr (EPI == 1) outb[idx] = f2b(v);
          else if constexpr (EPI == 2) outf[idx] = v + res[idx];
          else if constexpr (EPI == 3) outb[idx] = f2b(v / (1.f + __expf(-v)));
          else outb[idx] = f2b(v * b2f(aux[idx]));
        }
      }
    }
  }
}

// ---------------- GEMM 256x256 (r11/r14-validated): quadrant 8-phase, compiler lgkmcnt ----------------
// EPI 5: fused gate/up — Bt interleaved (per 256-row block: 128 gate | 128 up);
// qc=0 quadrants hold gate acc, qc=1 up acc; epilogue writes silu(g)*u to outb[.][N/2].
template <int EPI>
__global__ __launch_bounds__(512, 1) void gemm256(const unsigned short* __restrict__ A,
                                                  const unsigned short* __restrict__ Bt,
                                                  float* __restrict__ outf,
                                                  unsigned short* __restrict__ outb,
                                                  const float* __restrict__ res,
                                                  const unsigned short* __restrict__ aux,
                                                  int M, int N, int K) {
  __shared__ __align__(16) unsigned short Lds[2][2][2][128 * 64];
  const int tid = threadIdx.x;
  const int l = tid & 63, lr = l & 15, lg = l >> 4;
  const int w = tid >> 6, swr = w >> 2, swn = w & 3;   // 2x4 waves inside a quadrant

  const int gn = N >> 8;
  int lin = blockIdx.x;
  {
    const int nwg = gridDim.x;
    lin = (lin & 7) * (nwg >> 3) + (lin >> 3);   // XCD chunking (nwg%8==0)
  }
  const int npg = gn << 3;
  const int gid = lin / npg;
  const int idx = lin - gid * npg;
  const int m0 = (gid * 8 + (idx & 7)) * 256;
  const int n0 = (idx >> 3) * 256;

  const int NT = K >> 6;

  f32x4 acc[4][8] = {};   // [quadrant][fi*2+fj]

  // stage one half-tile (16KB): mat 0=A/1=B, rowhalf rh, K-tile t -> dbuf t&1
  auto stageh = [&](int mat, int rh, int t) {
    const unsigned short* src = mat ? Bt : A;
    const int rbase = (mat ? n0 : m0) + rh * 128;
    const int d = t & 1;
#pragma unroll
    for (int g = 0; g < 2; ++g) {
      const int c = g * 512 + tid;
      const int row = c >> 3;                 // 0..127
      const int kc = (c & 7) ^ (row & 7);     // pre-swizzled global source chunk
      gload_lds16(src + (size_t)(rbase + row) * K + t * 64 + kc * 8,
                  &Lds[d][mat][rh][(size_t)(g * 512 + (tid & ~63)) * 8]);
    }
  };

  // prologue: tile 0 fully + A0,B0 of tile 1
  stageh(0, 0, 0); stageh(1, 0, 0); stageh(0, 1, 0); stageh(1, 1, 0);
  if (NT > 1) {
    stageh(0, 0, 1); stageh(1, 0, 1);
    asm volatile("s_waitcnt vmcnt(4)" ::: "memory");
  } else {
    asm volatile("s_waitcnt vmcnt(0)" ::: "memory");
  }
  __builtin_amdgcn_s_barrier();
  __builtin_amdgcn_sched_barrier(0);

#define RD_A(qr, fi, kk)                                                                    \
  af[fi][kk] = *reinterpret_cast<const bf16x8*>(                                            \
      &Lds[d][0][qr][(swr * 64 + (fi) * 16 + lr) * 64 + (((kk) * 4 + lg) ^ (lr & 7)) * 8])
#define RD_B(qc, fj, kk)                                                                    \
  bfv[fj][kk] = *reinterpret_cast<const bf16x8*>(                                           \
      &Lds[d][1][qc][(swn * 32 + (fj) * 16 + lr) * 64 + (((kk) * 4 + lg) ^ (lr & 7)) * 8])
#define MFMAQ(q)                                                                            \
  _Pragma("unroll") for (int fi = 0; fi < 4; ++fi)                                          \
  _Pragma("unroll") for (int fj = 0; fj < 2; ++fj)                                          \
  _Pragma("unroll") for (int kk = 0; kk < 2; ++kk)                                          \
      acc[q][fi * 2 + fj] =                                                                 \
          __builtin_amdgcn_mfma_f32_16x16x32_bf16(af[fi][kk], bfv[fj][kk], acc[q][fi * 2 + fj], 0, 0, 0)

  for (int T = 0; T < NT; ++T) {
    const int d = T & 1;
    bf16x8 af[4][2], bfv[2][2];

    // ---- ph1: q=(0,0) — read A-rh0 (8) + B-rh0 (4); stage A-rh1(T+1); W2
    RD_A(0, 0, 0); RD_A(0, 0, 1); RD_A(0, 1, 0); RD_A(0, 1, 1);
    RD_A(0, 2, 0); RD_A(0, 2, 1); RD_A(0, 3, 0); RD_A(0, 3, 1);
    RD_B(0, 0, 0); RD_B(0, 0, 1); RD_B(0, 1, 0); RD_B(0, 1, 1);
    if (T + 1 < NT) stageh(0, 1, T + 1);
    __builtin_amdgcn_s_setprio(1);
    MFMAQ(0);
    __builtin_amdgcn_s_setprio(0);
    if (T + 1 < NT) asm volatile("s_waitcnt vmcnt(6)" ::: "memory");   // W2
    else            asm volatile("s_waitcnt vmcnt(0)" ::: "memory");
    __builtin_amdgcn_s_barrier();
    __builtin_amdgcn_sched_barrier(0);

    // ---- ph2: q=(0,1) — read B-rh1 (4, A reused); stage B-rh1(T+1)
    RD_B(1, 0, 0); RD_B(1, 0, 1); RD_B(1, 1, 0); RD_B(1, 1, 1);
    if (T + 1 < NT) stageh(1, 1, T + 1);
    __builtin_amdgcn_s_setprio(1);
    MFMAQ(1);
    __builtin_amdgcn_s_setprio(0);
    __builtin_amdgcn_s_barrier();
    __builtin_amdgcn_sched_barrier(0);

    // ---- ph3: q=(1,0) — read A-rh1 (8) + B-rh0 (4); stage A-rh0(T+2)
    RD_A(1, 0, 0); RD_A(1, 0, 1); RD_A(1, 1, 0); RD_A(1, 1, 1);
    RD_A(1, 2, 0); RD_A(1, 2, 1); RD_A(1, 3, 0); RD_A(1, 3, 1);
    RD_B(0, 0, 0); RD_B(0, 0, 1); RD_B(0, 1, 0); RD_B(0, 1, 1);
    if (T + 2 < NT) stageh(0, 0, T + 2);
    __builtin_amdgcn_s_setprio(1);
    MFMAQ(2);
    __builtin_amdgcn_s_setprio(0);
    __builtin_amdgcn_s_barrier();
    __builtin_amdgcn_sched_barrier(0);

    // ---- ph4: q=(1,1) — read B-rh1 (4, A reused); stage B-rh0(T+2); W1
    RD_B(1, 0, 0); RD_B(1, 0, 1); RD_B(1, 1, 0); RD_B(1, 1, 1);
    if (T + 2 < NT) stageh(1, 0, T + 2);
    __builtin_amdgcn_s_setprio(1);
    MFMAQ(3);
    __builtin_amdgcn_s_setprio(0);
    if (T + 2 < NT)      asm volatile("s_waitcnt vmcnt(8)" ::: "memory");  // W1
    else if (T + 1 < NT) asm volatile("s_waitcnt vmcnt(4)" ::: "memory");
    __builtin_amdgcn_s_barrier();
    __builtin_amdgcn_sched_barrier(0);
  }

#undef RD_A
#undef RD_B
#undef MFMAQ

  if constexpr (EPI == 5) {
    // fused gate/up: act[r][(n0>>1)+...] = silu(gate) * up; act stride = N/2
    const int actN = N >> 1;
#pragma unroll
    for (int qr = 0; qr < 2; ++qr) {
#pragma unroll
      for (int fi = 0; fi < 4; ++fi) {
#pragma unroll
        for (int fj = 0; fj < 2; ++fj) {
          const int r0 = m0 + qr * 128 + swr * 64 + fi * 16 + lg * 4;
          const int cA = (n0 >> 1) + swn * 32 + fj * 16 + lr;
#pragma unroll
          for (int j = 0; j < 4; ++j) {
            const float g = acc[qr * 2][fi * 2 + fj][j];
            const float u = acc[qr * 2 + 1][fi * 2 + fj][j];
            outb[(size_t)(r0 + j) * actN + cA] = f2b(g / (1.f + __expf(-g)) * u);
          }
        }
      }
    }
  } else {
#pragma unroll
    for (int q = 0; q < 4; ++q) {
      const int qr = q >> 1, qc = q & 1;
#pragma unroll
      for (int fi = 0; fi < 4; ++fi) {
#pragma unroll
        for (int fj = 0; fj < 2; ++fj) {
          const int r = m0 + qr * 128 + swr * 64 + fi * 16 + lg * 4;
          const int c = n0 + qc * 128 + swn * 32 + fj * 16 + lr;
#pragma unroll
          for (int j = 0; j < 4; ++j) {
            const size_t idx2 = (size_t)(r + j) * N + c;
            const float v = acc[q][fi * 2 + fj][j];
            if constexpr (EPI == 0) outf[idx2] = v;
            else if constexpr (EPI == 1) outb[idx2] = f2b(v);
            else if constexpr (EPI == 2) outf[idx2] = v + res[idx2];
            else if constexpr (EPI == 3) outb[idx2] = f2b(v / (1.f + __expf(-v)));
            else if constexpr (EPI == 4) outb[idx2] = f2b(v * b2f(aux[idx2]));
          }
        }
      }
    }
  }
}

// ---------------- RoPE on q rope-dims only (scale folded into wq_b) ----------------
__global__ __launch_bounds__(256) void rope_q(unsigned short* __restrict__ q,
                                              const int* __restrict__ positions) {
  const int row = blockIdx.x;
  const int pos = positions[row];
  unsigned short* qp = q + (size_t)row * 3072;
  const int tid = threadIdx.x;
#pragma unroll
  for (int i = 0; i < 2; ++i) {           // 16 heads x 32 pairs
    int e = i * 256 + tid;
    int hh = e >> 5, j = e & 31;
    int base = hh * 192 + 128;
    float x1 = b2f(qp[base + j]), x2 = b2f(qp[base + 32 + j]);
    float freq = __expf(-(float)j * (9.210340371976184f / 32.f));  // 10000^(-j/32)
    float sa, ca;
    __sincosf((float)pos * freq, &sa, &ca);
    qp[base + j] = f2b(x1 * ca - x2 * sa);
    qp[base + 32 + j] = f2b(x2 * ca + x1 * sa);
  }
}

// ---- build kh [B*T,16,192]: k_pass from kv[...,0:128], roped k_rot broadcast ----
__global__ __launch_bounds__(256) void repack_k(const unsigned short* __restrict__ kv,
                                                const float* __restrict__ ckv,
                                                const int* __restrict__ positions,
                                                unsigned short* __restrict__ kh) {
  const int row = blockIdx.x;
  const int tid = threadIdx.x;
  {
    const int hh = tid >> 4, db = tid & 15;
    u16x8 v = *reinterpret_cast<const u16x8*>(kv + (size_t)row * 4096 + hh * 256 + db * 8);
    *reinterpret_cast<u16x8*>(kh + (size_t)row * 3072 + hh * 192 + db * 8) = v;
  }
  __shared__ float o1[32], o2[32];
  if (tid < 32) {
    const int j = tid;
    float x1 = ckv[(size_t)row * 576 + 512 + j];
    float x2 = ckv[(size_t)row * 576 + 544 + j];
    const int pos = positions[row];
    float freq = __expf(-(float)j * (9.210340371976184f / 32.f));
    float sa, ca;
    __sincosf((float)pos * freq, &sa, &ca);
    o1[j] = x1 * ca - x2 * sa;
    o2[j] = x2 * ca + x1 * sa;
  }
  __syncthreads();
#pragma unroll
  for (int i = 0; i < 4; ++i) {
    int e = i * 256 + tid;
    int hh = e >> 6, d = e & 63;
    float v = (d < 32) ? o1[d] : o2[d - 32];
    kh[(size_t)row * 3072 + hh * 192 + 128 + d] = f2b(v);
  }
}

// ---- flash attention v5: QBLK=128, 8 waves, defer-max + ones-MFMA, qt-paired balance ----
__global__ __launch_bounds__(512) void mla_attn(const unsigned short* __restrict__ qh,  // [B*T][16][192]
                                                const unsigned short* __restrict__ kh,  // [B*T][16][192]
                                                const unsigned short* __restrict__ kv,  // [B*T][16][256]
                                                unsigned short* __restrict__ o) {       // [B*T][2048]
  const int T = 2048, H = 16;
  const int bx = blockIdx.x;            // 0..7
  const int b = blockIdx.y >> 4;
  const int h = blockIdx.y & 15;
  const int tid = threadIdx.x, w = tid >> 6, l = tid & 63;
  const int lg = l >> 4, lr = l & 15;

  __shared__ __align__(16) unsigned short Ks[64 * 200];
  __shared__ __align__(16) unsigned short Vts[128 * 64];   // block-swizzled
  __shared__ __align__(16) unsigned short Pl[8][16 * 72];
  __shared__ float exs[8][16];

  int krow[3], kcol[3];
#pragma unroll
  for (int i = 0; i < 3; ++i) { int c = i * 512 + tid; krow[i] = c / 24; kcol[i] = (c % 24) * 8; }
  const int vkvp = tid >> 4;          // 0..31 (pairs of kv rows)
  const int vf0 = (tid & 15) * 8;     // feature chunk

  const unsigned short* kbase0 = kh + (((size_t)b * T) * H + h) * 192;       // +t*3072
  const unsigned short* vbase0 = kv + (((size_t)b * T) * H + h) * 256 + 128; // +t*4096

  bf16x8 ones;
#pragma unroll
  for (int e = 0; e < 8; ++e) ones[e] = (__bf16)1.0f;

  for (int half = 0; half < 2; ++half) {
    const int qt = half ? (15 - bx) : bx;

    bf16x8 qa[6];
    {
      const size_t qrow = (size_t)b * T + qt * 128 + w * 16 + lr;
      const unsigned short* qp = qh + (qrow * H + h) * 192 + lg * 8;
#pragma unroll
      for (int kc = 0; kc < 6; ++kc)
        qa[kc] = *reinterpret_cast<const bf16x8*>(qp + kc * 32);
    }

    u16x8 kreg[3], vregA, vregB;
#pragma unroll
    for (int i = 0; i < 3; ++i)
      kreg[i] = *reinterpret_cast<const u16x8*>(kbase0 + (size_t)krow[i] * 3072 + kcol[i]);
    vregA = *reinterpret_cast<const u16x8*>(vbase0 + (size_t)(2 * vkvp) * 4096 + vf0);
    vregB = *reinterpret_cast<const u16x8*>(vbase0 + (size_t)(2 * vkvp + 1) * 4096 + vf0);

    f32x4 ot[8] = {};
    f32x4 lacc = {};
    float mrow[4] = {NEG_BIG, NEG_BIG, NEG_BIG, NEG_BIG};

    const int ktmax = 2 * qt + 1;
    for (int kt = 0; kt <= ktmax; ++kt) {
#pragma unroll
      for (int i = 0; i < 3; ++i)
        *reinterpret_cast<u16x8*>(&Ks[krow[i] * 200 + kcol[i]]) = kreg[i];
      {
        const int c7 = (vf0 >> 3) & 7;
#pragma unroll
        for (int e = 0; e < 8; ++e) {
          const int blk = (vkvp >> 2) ^ (e ^ c7);
          const unsigned val = (unsigned)(unsigned short)vregA[e] |
                               ((unsigned)(unsigned short)vregB[e] << 16);
          *reinterpret_cast<unsigned*>(&Vts[(vf0 + e) * 64 + blk * 8 + (vkvp & 3) * 2]) = val;
        }
      }
      __syncthreads();

      if (kt < ktmax) {
        const unsigned short* kb = kbase0 + (size_t)(kt + 1) * 64 * 3072;
        const unsigned short* vb = vbase0 + (size_t)(kt + 1) * 64 * 4096;
#pragma unroll
        for (int i = 0; i < 3; ++i)
          kreg[i] = *reinterpret_cast<const u16x8*>(kb + (size_t)krow[i] * 3072 + kcol[i]);
        vregA = *reinterpret_cast<const u16x8*>(vb + (size_t)(2 * vkvp) * 4096 + vf0);
        vregB = *reinterpret_cast<const u16x8*>(vb + (size_t)(2 * vkvp + 1) * 4096 + vf0);
      }

      f32x4 s4[4];
#pragma unroll
      for (int ni = 0; ni < 4; ++ni) {
        f32x4 a = {};
#pragma unroll
        for (int kc = 0; kc < 6; ++kc) {
          bf16x8 kf = *reinterpret_cast<const bf16x8*>(&Ks[(ni * 16 + lr) * 200 + kc * 32 + lg * 8]);
          a = __builtin_amdgcn_mfma_f32_16x16x32_bf16(qa[kc], kf, a, 0, 0, 0);
        }
        s4[ni] = a;
      }
      if (kt >= 2 * qt) {
#pragma unroll
        for (int ni = 0; ni < 4; ++ni) {
          const int colr = ni * 16 + lr;
#pragma unroll
          for (int j = 0; j < 4; ++j) {
            const int qrl = qt * 128 + w * 16 + lg * 4 + j - kt * 64;
            if (colr > qrl) s4[ni][j] = NEG_BIG;
          }
        }
      }

      // T13 defer-max
      float pmj[4];
      int need = 0;
#pragma unroll
      for (int j = 0; j < 4; ++j) {
        pmj[j] = fmaxf(fmaxf(s4[0][j], s4[1][j]), fmaxf(s4[2][j], s4[3][j]));
        need |= (pmj[j] > mrow[j] + 8.f) ? 1 : 0;
      }
      if (__any(need)) {
        float al[4];
#pragma unroll
        for (int j = 0; j < 4; ++j) {
          float rm = pmj[j];
#pragma unroll
          for (int m = 1; m < 16; m <<= 1) rm = fmaxf(rm, __shfl_xor(rm, m));
          const float mn = fmaxf(mrow[j], rm);
          al[j] = __expf(mrow[j] - mn);
          mrow[j] = mn;
        }
        if (lr == 0) {
#pragma unroll
          for (int j = 0; j < 4; ++j) exs[w][lg * 4 + j] = al[j];
        }
        const float af = exs[w][lr];
#pragma unroll
        for (int mi = 0; mi < 8; ++mi) {
          ot[mi][0] *= af; ot[mi][1] *= af; ot[mi][2] *= af; ot[mi][3] *= af;
        }
        lacc[0] *= af; lacc[1] *= af; lacc[2] *= af; lacc[3] *= af;
      }

#pragma unroll
      for (int ni = 0; ni < 4; ++ni)
#pragma unroll
        for (int j = 0; j < 4; ++j)
          Pl[w][(lg * 4 + j) * 72 + ni * 16 + lr] = f2b(__expf(s4[ni][j] - mrow[j]));

      bf16x8 pf0 = *reinterpret_cast<const bf16x8*>(&Pl[w][lr * 72 + lg * 8]);
      bf16x8 pf1 = *reinterpret_cast<const bf16x8*>(&Pl[w][lr * 72 + 32 + lg * 8]);
      lacc = __builtin_amdgcn_mfma_f32_16x16x32_bf16(ones, pf0, lacc, 0, 0, 0);
      lacc = __builtin_amdgcn_mfma_f32_16x16x32_bf16(ones, pf1, lacc, 0, 0, 0);
#pragma unroll
      for (int mi = 0; mi < 8; ++mi) {
        const int f = mi * 16 + lr;
        const int sfz = (f & 7) ^ ((f >> 3) & 7);
        const int blk0 = lg ^ sfz;
        const int blk1 = (4 + lg) ^ sfz;
        bf16x8 vf0r = *reinterpret_cast<const bf16x8*>(&Vts[f * 64 + blk0 * 8]);
        ot[mi] = __builtin_amdgcn_mfma_f32_16x16x32_bf16(vf0r, pf0, ot[mi], 0, 0, 0);
        bf16x8 vf1r = *reinterpret_cast<const bf16x8*>(&Vts[f * 64 + blk1 * 8]);
        ot[mi] = __builtin_amdgcn_mfma_f32_16x16x32_bf16(vf1r, pf1, ot[mi], 0, 0, 0);
      }
      __syncthreads();
    }

    const float li = 1.f / lacc[0];
    const size_t orow = (size_t)b * T + qt * 128 + w * 16 + lr;
#pragma unroll
    for (int mi = 0; mi < 8; ++mi)
#pragma unroll
      for (int j = 0; j < 4; ++j) {
        const int feat = mi * 16 + lg * 4 + j;
        o[orow * 2048 + h * 128 + feat] = f2b(ot[mi][j] * li);
      }
  }
}

// ---------------- host ----------------
extern "C" void kernel_launch(void* const* d_in, const int* in_sizes, int n_in,
                              void* d_out, int out_size, void* d_ws, size_t ws_size,
                              hipStream_t stream) {
  (void)in_sizes; (void)n_in;
  const float* x      = (const float*)d_in[0];
  const float* ln1_w  = (const float*)d_in[1];
  const float* wq_a   = (const float*)d_in[2];
  const float* qaln_w = (const float*)d_in[3];
  const float* wq_b   = (const float*)d_in[4];
  const float* wkv_a  = (const float*)d_in[5];
  const float* kvln_w = (const float*)d_in[6];
  const float* wkv_b  = (const float*)d_in[7];
  const float* wo     = (const float*)d_in[8];
  const float* ln2_w  = (const float*)d_in[9];
  const float* w_gate = (const float*)d_in[10];
  const float* w_up   = (const float*)d_in[11];
  const float* w_down = (const float*)d_in[12];
  const int*   pos    = (const int*)d_in[14];
  float* out = (float*)d_out;

  const int Mt = 8192;  // B*T

  char* ws = (char*)d_ws;
  const size_t R1 = 0;                          // qa_b16 -> kvbuf
  const size_t R2 = R1 + 67108864;              // qbuf
  const size_t R3 = R2 + 50331648;              // qan -> ckvn -> khbuf
  const size_t R4 = R3 + 50331648;              // hbuf -> obuf
  const size_t R5 = R4 + 33554432;              // ckv (f32)
  const size_t R6 = R5 + 18874368;              // weight slot (9.4MB)
  const size_t REQ = R6 + 9437184;              // 229,638,144 total

  if (ws_size < REQ) {
    fill_sentinel<<<dim3((out_size + 255) / 256), dim3(256), 0, stream>>>(
        out, out_size, (float)(ws_size >> 20));
    return;
  }

  unsigned short* qa_b16 = (unsigned short*)(ws + R1);
  unsigned short* kvbuf  = (unsigned short*)(ws + R1);
  unsigned short* qbuf   = (unsigned short*)(ws + R2);
  unsigned short* qan    = (unsigned short*)(ws + R3);
  unsigned short* ckvn   = (unsigned short*)(ws + R3);
  unsigned short* khbuf  = (unsigned short*)(ws + R3);
  unsigned short* hbuf   = (unsigned short*)(ws + R4);
  unsigned short* obuf   = (unsigned short*)(ws + R4);
  float*          ckv    = (float*)(ws + R5);
  unsigned short* slotW  = (unsigned short*)(ws + R6);
  // MLP-phase overlay (all attention-phase buffers dead by then):
  unsigned short* actb  = (unsigned short*)(ws + 0);           // act half: 8192x4096 bf16 = 64MB
  unsigned short* h2b   = (unsigned short*)(ws + 134217728);   // 32MB
  unsigned short* wsl2  = (unsigned short*)(ws + 167772160);   // interleaved W: 8192x2048 bf16 = 32MB

  dim3 blk(256);
  dim3 blk5(512);
  auto tcf = [&](const float* W, int K, int N, float scale) {
    transpose_convert<<<dim3((N + 31) / 32, (K + 31) / 32), blk, 0, stream>>>(W, slotW, K, N, N, 0, 0, scale, -1);
  };
  auto g256 = [&](auto epi, const unsigned short* Aa, const unsigned short* Bb, float* of,
                  unsigned short* ob, const float* rs, const unsigned short* ax, int N, int K) {
    gemm256<decltype(epi)::value><<<dim3(32 * (N >> 8)), blk5, 0, stream>>>(Aa, Bb, of, ob, rs, ax, Mt, N, K);
  };

  // h = rmsnorm(x)
  rmsnorm_kernel<<<Mt, blk, 0, stream>>>(x, ln1_w, hbuf, 2048, 2048, 2048);
  // q_a = h @ wq_a (bf16) ; rmsnorm(bf16) -> qan
  tcf(wq_a, 2048, 1536, 1.0f);
  g256(std::integral_constant<int,1>{}, hbuf, slotW, nullptr, qa_b16, nullptr, nullptr, 1536, 2048);
  rmsnorm_b16<<<Mt, blk, 0, stream>>>(qa_b16, qaln_w, qan, 1536);
  // q = qan @ (wq_b * SCALE) (bf16)
  tcf(wq_b, 1536, 3072, 0.07216878364870322f);
  g256(std::integral_constant<int,1>{}, qan, slotW, nullptr, qbuf, nullptr, nullptr, 3072, 1536);
  // ckv = h @ wkv_a (f32, N=576 -> m97 path) ; rmsnorm(k_c) -> ckvn
  tcf(wkv_a, 2048, 576, 1.0f);
  gemm_bt<0><<<dim3(5, 64), blk, 0, stream>>>(hbuf, slotW, ckv, nullptr, nullptr, nullptr, Mt, 576, 2048);
  rmsnorm_kernel<<<Mt, blk, 0, stream>>>(ckv, kvln_w, ckvn, 512, 576, 512);
  // kv = ckvn @ wkv_b (bf16)
  tcf(wkv_b, 512, 4096, 1.0f);
  g256(std::integral_constant<int,1>{}, ckvn, slotW, nullptr, kvbuf, nullptr, nullptr, 4096, 512);
  // rope q (rope dims only); build kh
  rope_q<<<Mt, blk, 0, stream>>>(qbuf, pos);
  repack_k<<<Mt, blk, 0, stream>>>(kvbuf, ckv, pos, khbuf);
  // attention -> obuf   (qt-paired: grid 8 x 64, 512 threads, uniform 34 tiles/block)
  mla_attn<<<dim3(8, 64), blk5, 0, stream>>>(qbuf, khbuf, kvbuf, obuf);
  // x1 = x + o @ wo   (x1 lives in d_out)
  tcf(wo, 2048, 2048, 1.0f);
  g256(std::integral_constant<int,2>{}, obuf, slotW, out, nullptr, x, nullptr, 2048, 2048);
  // h2 = rmsnorm(x1)
  rmsnorm_kernel<<<Mt, blk, 0, stream>>>(out, ln2_w, h2b, 2048, 2048, 2048);
  // MLP in 2 halves of D_FF=4096, fused gate/up (interleaved weights, EPI=5):
  //   act = silu(h2@Wg_c) * (h2@Wu_c); out += act @ Wd_c
  for (int c = 0; c < 2; ++c) {
    transpose_convert<<<dim3(128, 64), blk, 0, stream>>>(w_gate, wsl2, 2048, 4096, 8192, 0, c * 4096, 1.0f, 0);
    transpose_convert<<<dim3(128, 64), blk, 0, stream>>>(w_up,   wsl2, 2048, 4096, 8192, 0, c * 4096, 1.0f, 128);
    g256(std::integral_constant<int,5>{}, h2b, wsl2, nullptr, actb, nullptr, nullptr, 8192, 2048);
    transpose_convert<<<dim3(64, 128), blk, 0, stream>>>(w_down, wsl2, 4096, 2048, 2048, c * 4096, 0, 1.0f, -1);
    g256(std::integral_constant<int,2>{}, actb, wsl2, out, nullptr, out, nullptr, 2048, 4096);
  }
}